// Round 1
// baseline (405.019 us; speedup 1.0000x reference)
//
#include <hip/hip_runtime.h>
#include <math.h>

// Problem constants
#define BB 128
#define N0 128
#define N1 128
#define ND 32
#define NIJ (N0 * N1)           // 16384
#define EPS2 0.25f
#define EPS4 0.0625f

// ws layout (float offsets)
#define OFF_CA   0                        // [ND][NIJ] coefA = -0.5/Sigma
#define OFF_CB   (OFF_CA + ND * NIJ)      // [ND][NIJ] coefB = Mut/Sigma
#define OFF_K    (OFF_CB + ND * NIJ)      // [ND][NIJ] K = St/Sigma
#define OFF_KV   (OFF_K  + ND * NIJ)      // [ND][NIJ] KV = v - K*Mut
#define OFF_CC   (OFF_KV + ND * NIJ)      // [NIJ]     Cc = sum_n (cA*Mut^2 - 0.5*log Sigma)
#define OFF_NUM  (OFF_CC + NIJ)           // [BB][ND]  accumulated numerator
#define OFF_DEN  (OFF_NUM + BB * ND)      // [BB]      accumulated denominator
#define ZERO_CNT (BB * ND + BB)           // floats to zero (acc region)

__global__ __launch_bounds__(256) void gmm_precompute(
    const float* __restrict__ tptr,
    const float* __restrict__ Mu0, const float* __restrict__ Mu1,
    const float* __restrict__ S0,  const float* __restrict__ S1,
    float* __restrict__ ws)
{
    int ij = blockIdx.x * blockDim.x + threadIdx.x;   // 16384 threads
    if (ij >= NIJ) return;

    // zero the accumulator region (ws is poisoned 0xAA before every launch)
    if (ij < ZERO_CNT) ws[OFF_NUM + ij] = 0.0f;

    const float t   = tptr[0];
    const float omt = 1.0f - t;
    const int i = ij >> 7;       // N1 = 128
    const int j = ij & 127;

    float csum = 0.0f;
#pragma unroll
    for (int n = 0; n < ND; ++n) {
        float s0 = S0[i * ND + n];
        float s1 = S1[j * ND + n];
        float Ds = sqrtf(4.0f * s0 * s1 + EPS4);
        float Cs = 0.5f * (Ds - EPS2);
        float Sigma = omt * omt * s0 + t * t * s1 + 2.0f * t * omt * Cs + EPS2 * t * omt;
        float Pt = t * s1 + omt * Cs;
        float Qt = omt * s0 + t * Cs;
        float St = Pt - Qt - EPS2 * t;
        float mu0 = Mu0[i * ND + n];
        float mu1 = Mu1[j * ND + n];
        float Mut = omt * mu0 + t * mu1;
        float v   = mu1 - mu0;
        float invS = 1.0f / Sigma;
        float Kf  = St * invS;
        float cA  = -0.5f * invS;
        float cB  = Mut * invS;
        csum += cA * Mut * Mut - 0.5f * logf(Sigma);
        ws[OFF_CA + n * NIJ + ij] = cA;
        ws[OFF_CB + n * NIJ + ij] = cB;
        ws[OFF_K  + n * NIJ + ij] = Kf;
        ws[OFF_KV + n * NIJ + ij] = v - Kf * Mut;
    }
    ws[OFF_CC + ij] = csum;
}

#define CHUNKS 4
#define IJ_PER_CHUNK (NIJ / CHUNKS)         // 4096
#define ITERS (IJ_PER_CHUNK / 256)          // 16

__global__ __launch_bounds__(256) void gmm_main(
    const float* __restrict__ X,
    const float* __restrict__ Lam,
    const float* __restrict__ ws,
    float* __restrict__ accNum,   // ws + OFF_NUM
    float* __restrict__ accDen)   // ws + OFF_DEN
{
    const int b     = blockIdx.x >> 2;      // CHUNKS = 4
    const int chunk = blockIdx.x & (CHUNKS - 1);

    float Xr[ND], X2r[ND];
#pragma unroll
    for (int n = 0; n < ND; ++n) {
        float x = X[b * ND + n];
        Xr[n]  = x;
        X2r[n] = x * x;
    }

    float num[ND];
#pragma unroll
    for (int n = 0; n < ND; ++n) num[n] = 0.0f;
    float den = 0.0f;

    const float* __restrict__ cA = ws + OFF_CA;
    const float* __restrict__ cB = ws + OFF_CB;
    const float* __restrict__ Km = ws + OFF_K;
    const float* __restrict__ Kv = ws + OFF_KV;
    const float* __restrict__ Cc = ws + OFF_CC;

    int ij = chunk * IJ_PER_CHUNK + threadIdx.x;
    for (int it = 0; it < ITERS; ++it, ij += 256) {
        float lw = Cc[ij];
#pragma unroll
        for (int n = 0; n < ND; ++n) {
            lw = fmaf(cA[n * NIJ + ij], X2r[n], lw);
            lw = fmaf(cB[n * NIJ + ij], Xr[n], lw);
        }
        lw = fminf(fmaxf(lw, -50.0f), 50.0f);
        float w = __expf(lw) * Lam[ij];
        den += w;
#pragma unroll
        for (int n = 0; n < ND; ++n) {
            float u = fmaf(Km[n * NIJ + ij], Xr[n], Kv[n * NIJ + ij]);
            num[n] = fmaf(w, u, num[n]);
        }
    }

    // wave (64-lane) reduction
#pragma unroll
    for (int off = 32; off > 0; off >>= 1) {
        den += __shfl_down(den, off);
#pragma unroll
        for (int n = 0; n < ND; ++n) num[n] += __shfl_down(num[n], off);
    }

    if ((threadIdx.x & 63) == 0) {
        atomicAdd(&accDen[b], den);
#pragma unroll
        for (int n = 0; n < ND; ++n) atomicAdd(&accNum[b * ND + n], num[n]);
    }
}

__global__ __launch_bounds__(256) void gmm_finalize(
    const float* __restrict__ accNum,
    const float* __restrict__ accDen,
    float* __restrict__ out)
{
    int gid = blockIdx.x * blockDim.x + threadIdx.x;
    if (gid >= BB * ND) return;
    int b = gid >> 5;   // ND = 32
    out[gid] = accNum[gid] / accDen[b];
}

extern "C" void kernel_launch(void* const* d_in, const int* in_sizes, int n_in,
                              void* d_out, int out_size, void* d_ws, size_t ws_size,
                              hipStream_t stream)
{
    const float* X   = (const float*)d_in[0];
    const float* t   = (const float*)d_in[1];
    const float* Mu0 = (const float*)d_in[2];
    const float* Mu1 = (const float*)d_in[3];
    const float* S0  = (const float*)d_in[4];
    const float* S1  = (const float*)d_in[5];
    const float* Lam = (const float*)d_in[6];
    float* out = (float*)d_out;
    float* ws  = (float*)d_ws;

    // Kernel 1: per-(i,j) coefficient precompute + accumulator zeroing
    gmm_precompute<<<NIJ / 256, 256, 0, stream>>>(t, Mu0, Mu1, S0, S1, ws);

    // Kernel 2: main weighted accumulation
    gmm_main<<<BB * CHUNKS, 256, 0, stream>>>(X, Lam, ws,
                                              ws + OFF_NUM, ws + OFF_DEN);

    // Kernel 3: finalize out = num / den
    gmm_finalize<<<(BB * ND + 255) / 256, 256, 0, stream>>>(ws + OFF_NUM,
                                                            ws + OFF_DEN, out);
}

// Round 2
// 267.581 us; speedup vs baseline: 1.5136x; 1.5136x over previous
//
#include <hip/hip_runtime.h>
#include <math.h>

// Problem constants
#define BB 128
#define N0C 128
#define N1C 128
#define ND 32
#define NIJ (N0C * N1C)     // 16384
#define EPS2 0.25f
#define EPS4 0.0625f

// Tiling
#define TIJ 64              // ij per block
#define NBLK (NIJ / TIJ)    // 256 blocks (1 per CU)
#define NTHR 512            // threads per block (8 waves)
#define QN 8                // ij-groups per b-pair group
#define IJT (TIJ / QN)      // 8 ij per thread
#define ROWF 132            // 128 coef floats + 4 pad (bank decorrelation)

// ws accumulator layout
#define ACC_NUM 0           // [BB][ND]
#define ACC_DEN (BB * ND)   // [BB]
#define ACC_CNT (BB * ND + BB)

__global__ __launch_bounds__(NTHR, 2) void gmm_fused(
    const float* __restrict__ X,
    const float* __restrict__ tptr,
    const float* __restrict__ Mu0, const float* __restrict__ Mu1,
    const float* __restrict__ S0,  const float* __restrict__ S1,
    const float* __restrict__ Lam,
    float* __restrict__ accNum, float* __restrict__ accDen)
{
    __shared__ __align__(16) float coef[TIJ][ROWF]; // [cA|cB|K|KV] per ij
    __shared__ float CcS[TIJ];
    __shared__ float LamS[TIJ];

    const int tid = threadIdx.x;
    const int ij0 = blockIdx.x * TIJ;
    const float t   = tptr[0];
    const float omt = 1.0f - t;

    // ---- Phase 1: per-(ij, n) coefficient computation into LDS ----
    // 64 ij * 32 n = 2048 pairs over 512 threads -> 4 each
#pragma unroll
    for (int k = 0; k < (TIJ * ND) / NTHR; ++k) {
        const int idx = tid + k * NTHR;
        const int ijl = idx >> 5;          // 0..63
        const int n   = idx & 31;
        const int ij  = ij0 + ijl;
        const int i   = ij >> 7;
        const int j   = ij & 127;
        const float s0  = S0[i * ND + n];
        const float s1  = S1[j * ND + n];
        const float mu0 = Mu0[i * ND + n];
        const float mu1 = Mu1[j * ND + n];
        const float Ds  = sqrtf(4.0f * s0 * s1 + EPS4);
        const float Cs  = 0.5f * (Ds - EPS2);
        const float Sigma = omt * omt * s0 + t * t * s1
                          + 2.0f * t * omt * Cs + EPS2 * t * omt;
        const float St  = (t * s1 + omt * Cs) - (omt * s0 + t * Cs) - EPS2 * t;
        const float Mut = omt * mu0 + t * mu1;
        const float v   = mu1 - mu0;
        const float invS = 1.0f / Sigma;
        const float Kf  = St * invS;
        const float cA  = -0.5f * invS;
        const float cB  = Mut * invS;
        coef[ijl][n]      = cA;
        coef[ijl][32 + n] = cB;
        coef[ijl][64 + n] = Kf;
        coef[ijl][96 + n] = v - Kf * Mut;
        // Cc[ij] = sum_n (cA*Mut^2 - 0.5*log Sigma): reduce across the 32
        // n-lanes (consecutive, 32-aligned within the wave)
        float cc = cA * Mut * Mut - 0.5f * __logf(Sigma);
        cc += __shfl_xor(cc, 1);
        cc += __shfl_xor(cc, 2);
        cc += __shfl_xor(cc, 4);
        cc += __shfl_xor(cc, 8);
        cc += __shfl_xor(cc, 16);
        if (n == 0) CcS[ijl] = cc;
    }
    if (tid < TIJ) LamS[tid] = Lam[ij0 + tid];

    // ---- X for this thread's two b values -> registers ----
    const int g  = tid >> 3;       // 0..63: b-pair index
    const int q  = tid & 7;        // ij-group
    const int b0 = 2 * g;
    const int b1 = 2 * g + 1;
    float x0[ND], x1[ND];
#pragma unroll
    for (int c = 0; c < 8; ++c) {
        const float4 v0 = ((const float4*)(X + b0 * ND))[c];
        const float4 v1 = ((const float4*)(X + b1 * ND))[c];
        x0[4*c+0] = v0.x; x0[4*c+1] = v0.y; x0[4*c+2] = v0.z; x0[4*c+3] = v0.w;
        x1[4*c+0] = v1.x; x1[4*c+1] = v1.y; x1[4*c+2] = v1.z; x1[4*c+3] = v1.w;
    }

    float num0[ND], num1[ND];
#pragma unroll
    for (int n = 0; n < ND; ++n) { num0[n] = 0.0f; num1[n] = 0.0f; }
    float den0 = 0.0f, den1 = 0.0f;

    __syncthreads();

    // ---- Phase 2: main accumulation. Thread: 2 b x 8 ij ----
    for (int it = 0; it < IJT; ++it) {
        const int ijl = q + it * QN;   // 8 distinct bank-disjoint rows per wave
        const float* __restrict__ row = &coef[ijl][0];
        float lw0 = CcS[ijl];
        float lw1 = lw0;
#pragma unroll
        for (int nc = 0; nc < 8; ++nc) {
            const float4 a  = *(const float4*)&row[nc * 4];
            const float4 bq = *(const float4*)&row[32 + nc * 4];
#define LOGW_STEP(comp, nn) \
            lw0 = fmaf(fmaf(a.comp, x0[nn], bq.comp), x0[nn], lw0); \
            lw1 = fmaf(fmaf(a.comp, x1[nn], bq.comp), x1[nn], lw1);
            LOGW_STEP(x, nc*4+0) LOGW_STEP(y, nc*4+1)
            LOGW_STEP(z, nc*4+2) LOGW_STEP(w, nc*4+3)
#undef LOGW_STEP
        }
        const float lam = LamS[ijl];
        lw0 = fminf(fmaxf(lw0, -50.0f), 50.0f);
        lw1 = fminf(fmaxf(lw1, -50.0f), 50.0f);
        const float w0 = __expf(lw0) * lam;
        const float w1 = __expf(lw1) * lam;
        den0 += w0;
        den1 += w1;
#pragma unroll
        for (int nc = 0; nc < 8; ++nc) {
            const float4 kk = *(const float4*)&row[64 + nc * 4];
            const float4 kv = *(const float4*)&row[96 + nc * 4];
#define NUM_STEP(comp, nn) \
            num0[nn] = fmaf(w0, fmaf(kk.comp, x0[nn], kv.comp), num0[nn]); \
            num1[nn] = fmaf(w1, fmaf(kk.comp, x1[nn], kv.comp), num1[nn]);
            NUM_STEP(x, nc*4+0) NUM_STEP(y, nc*4+1)
            NUM_STEP(z, nc*4+2) NUM_STEP(w, nc*4+3)
#undef NUM_STEP
        }
    }

    // ---- Reduce across the 8 q-lanes (consecutive lanes, same wave) ----
#pragma unroll
    for (int m = 1; m <= 4; m <<= 1) {
        den0 += __shfl_xor(den0, m);
        den1 += __shfl_xor(den1, m);
#pragma unroll
        for (int n = 0; n < ND; ++n) {
            num0[n] += __shfl_xor(num0[n], m);
            num1[n] += __shfl_xor(num1[n], m);
        }
    }

    if (q == 0) {
        atomicAdd(&accDen[b0], den0);
        atomicAdd(&accDen[b1], den1);
#pragma unroll
        for (int n = 0; n < ND; ++n) {
            atomicAdd(&accNum[b0 * ND + n], num0[n]);
            atomicAdd(&accNum[b1 * ND + n], num1[n]);
        }
    }
}

__global__ __launch_bounds__(256) void gmm_finalize(
    const float* __restrict__ accNum,
    const float* __restrict__ accDen,
    float* __restrict__ out)
{
    const int gid = blockIdx.x * blockDim.x + threadIdx.x;
    if (gid >= BB * ND) return;
    out[gid] = accNum[gid] / accDen[gid >> 5];
}

extern "C" void kernel_launch(void* const* d_in, const int* in_sizes, int n_in,
                              void* d_out, int out_size, void* d_ws, size_t ws_size,
                              hipStream_t stream)
{
    const float* X   = (const float*)d_in[0];
    const float* t   = (const float*)d_in[1];
    const float* Mu0 = (const float*)d_in[2];
    const float* Mu1 = (const float*)d_in[3];
    const float* S0  = (const float*)d_in[4];
    const float* S1  = (const float*)d_in[5];
    const float* Lam = (const float*)d_in[6];
    float* out = (float*)d_out;
    float* acc = (float*)d_ws;

    // zero accumulators (ws is poisoned 0xAA before every launch)
    hipMemsetAsync(d_ws, 0, ACC_CNT * sizeof(float), stream);

    gmm_fused<<<NBLK, NTHR, 0, stream>>>(X, t, Mu0, Mu1, S0, S1, Lam,
                                         acc + ACC_NUM, acc + ACC_DEN);

    gmm_finalize<<<(BB * ND + 255) / 256, 256, 0, stream>>>(acc + ACC_NUM,
                                                            acc + ACC_DEN, out);
}

// Round 3
// 86.459 us; speedup vs baseline: 4.6845x; 3.0949x over previous
//
#include <hip/hip_runtime.h>
#include <math.h>

// Problem constants
#define BB 128
#define N0C 128
#define N1C 128
#define ND 32
#define NIJ (N0C * N1C)     // 16384
#define EPS2 0.25f
#define EPS4 0.0625f

// Tiling
#define TIJ 64              // ij per block
#define NBLK (NIJ / TIJ)    // 256 blocks (1 per CU)
#define NTHR 512            // threads per block (8 waves)
#define QN 8                // ij-groups per b-pair group
#define IJT (TIJ / QN)      // 8 ij per thread
#define ROWF 132            // 128 coef floats + 4 pad (bank decorrelation)

// Partial-sum layout: part[blk][b][PS]  (PS=36 keeps 16B alignment per b)
#define PS 36
#define PART_PER_BLK (BB * PS)          // 4608 floats / block (18 KB)

__global__ __launch_bounds__(NTHR, 2) void gmm_fused(
    const float* __restrict__ X,
    const float* __restrict__ tptr,
    const float* __restrict__ Mu0, const float* __restrict__ Mu1,
    const float* __restrict__ S0,  const float* __restrict__ S1,
    const float* __restrict__ Lam,
    float* __restrict__ part)
{
    __shared__ __align__(16) float coef[TIJ][ROWF]; // [cA|cB|K|KV] per ij
    __shared__ float CcS[TIJ];
    __shared__ float LamS[TIJ];

    const int tid = threadIdx.x;
    const int ij0 = blockIdx.x * TIJ;
    const float t   = tptr[0];
    const float omt = 1.0f - t;

    // ---- Phase 1: per-(ij, n) coefficient computation into LDS ----
#pragma unroll
    for (int k = 0; k < (TIJ * ND) / NTHR; ++k) {
        const int idx = tid + k * NTHR;
        const int ijl = idx >> 5;          // 0..63
        const int n   = idx & 31;
        const int ij  = ij0 + ijl;
        const int i   = ij >> 7;
        const int j   = ij & 127;
        const float s0  = S0[i * ND + n];
        const float s1  = S1[j * ND + n];
        const float mu0 = Mu0[i * ND + n];
        const float mu1 = Mu1[j * ND + n];
        const float Ds  = sqrtf(4.0f * s0 * s1 + EPS4);
        const float Cs  = 0.5f * (Ds - EPS2);
        const float Sigma = omt * omt * s0 + t * t * s1
                          + 2.0f * t * omt * Cs + EPS2 * t * omt;
        const float St  = (t * s1 + omt * Cs) - (omt * s0 + t * Cs) - EPS2 * t;
        const float Mut = omt * mu0 + t * mu1;
        const float v   = mu1 - mu0;
        const float invS = 1.0f / Sigma;
        const float Kf  = St * invS;
        const float cA  = -0.5f * invS;
        const float cB  = Mut * invS;
        coef[ijl][n]      = cA;
        coef[ijl][32 + n] = cB;
        coef[ijl][64 + n] = Kf;
        coef[ijl][96 + n] = v - Kf * Mut;
        float cc = cA * Mut * Mut - 0.5f * __logf(Sigma);
        cc += __shfl_xor(cc, 1);
        cc += __shfl_xor(cc, 2);
        cc += __shfl_xor(cc, 4);
        cc += __shfl_xor(cc, 8);
        cc += __shfl_xor(cc, 16);
        if (n == 0) CcS[ijl] = cc;
    }
    if (tid < TIJ) LamS[tid] = Lam[ij0 + tid];

    // ---- X for this thread's two b values -> registers ----
    const int g  = tid >> 3;       // 0..63: b-pair index
    const int q  = tid & 7;        // ij-group
    const int b0 = 2 * g;
    const int b1 = 2 * g + 1;
    float x0[ND], x1[ND];
#pragma unroll
    for (int c = 0; c < 8; ++c) {
        const float4 v0 = ((const float4*)(X + b0 * ND))[c];
        const float4 v1 = ((const float4*)(X + b1 * ND))[c];
        x0[4*c+0] = v0.x; x0[4*c+1] = v0.y; x0[4*c+2] = v0.z; x0[4*c+3] = v0.w;
        x1[4*c+0] = v1.x; x1[4*c+1] = v1.y; x1[4*c+2] = v1.z; x1[4*c+3] = v1.w;
    }

    float num0[ND], num1[ND];
#pragma unroll
    for (int n = 0; n < ND; ++n) { num0[n] = 0.0f; num1[n] = 0.0f; }
    float den0 = 0.0f, den1 = 0.0f;

    __syncthreads();

    // ---- Phase 2: main accumulation. Thread: 2 b x 8 ij ----
    for (int it = 0; it < IJT; ++it) {
        const int ijl = q + it * QN;   // 8 distinct bank-disjoint rows per wave
        const float* __restrict__ row = &coef[ijl][0];
        const float cc0 = CcS[ijl];
        // two accumulation chains per b for ILP
        float lw0a = cc0, lw0b = 0.0f, lw1a = cc0, lw1b = 0.0f;
#pragma unroll
        for (int nc = 0; nc < 8; ++nc) {
            const float4 a  = *(const float4*)&row[nc * 4];
            const float4 bq = *(const float4*)&row[32 + nc * 4];
#define LOGW_STEP(comp, nn) \
            lw0a = fmaf(fmaf(a.comp, x0[nn], bq.comp), x0[nn], lw0a); \
            lw1a = fmaf(fmaf(a.comp, x1[nn], bq.comp), x1[nn], lw1a);
#define LOGW_STEPB(comp, nn) \
            lw0b = fmaf(fmaf(a.comp, x0[nn], bq.comp), x0[nn], lw0b); \
            lw1b = fmaf(fmaf(a.comp, x1[nn], bq.comp), x1[nn], lw1b);
            LOGW_STEP(x, nc*4+0) LOGW_STEPB(y, nc*4+1)
            LOGW_STEP(z, nc*4+2) LOGW_STEPB(w, nc*4+3)
#undef LOGW_STEP
#undef LOGW_STEPB
        }
        const float lam = LamS[ijl];
        float lw0 = lw0a + lw0b;
        float lw1 = lw1a + lw1b;
        lw0 = fminf(fmaxf(lw0, -50.0f), 50.0f);
        lw1 = fminf(fmaxf(lw1, -50.0f), 50.0f);
        const float w0 = __expf(lw0) * lam;
        const float w1 = __expf(lw1) * lam;
        den0 += w0;
        den1 += w1;
#pragma unroll
        for (int nc = 0; nc < 8; ++nc) {
            const float4 kk = *(const float4*)&row[64 + nc * 4];
            const float4 kv = *(const float4*)&row[96 + nc * 4];
#define NUM_STEP(comp, nn) \
            num0[nn] = fmaf(w0, fmaf(kk.comp, x0[nn], kv.comp), num0[nn]); \
            num1[nn] = fmaf(w1, fmaf(kk.comp, x1[nn], kv.comp), num1[nn]);
            NUM_STEP(x, nc*4+0) NUM_STEP(y, nc*4+1)
            NUM_STEP(z, nc*4+2) NUM_STEP(w, nc*4+3)
#undef NUM_STEP
        }
    }

    // ---- Reduce across the 8 q-lanes (consecutive lanes, same wave) ----
#pragma unroll
    for (int m = 1; m <= 4; m <<= 1) {
        den0 += __shfl_xor(den0, m);
        den1 += __shfl_xor(den1, m);
#pragma unroll
        for (int n = 0; n < ND; ++n) {
            num0[n] += __shfl_xor(num0[n], m);
            num1[n] += __shfl_xor(num1[n], m);
        }
    }

    // ---- Plain (non-atomic) partial store into this block's private slice ----
    if (q == 0) {
        float* dst0 = part + blockIdx.x * PART_PER_BLK + b0 * PS;
        float* dst1 = dst0 + PS;
#pragma unroll
        for (int c = 0; c < 8; ++c) {
            *(float4*)(dst0 + 4 * c) =
                make_float4(num0[4*c], num0[4*c+1], num0[4*c+2], num0[4*c+3]);
            *(float4*)(dst1 + 4 * c) =
                make_float4(num1[4*c], num1[4*c+1], num1[4*c+2], num1[4*c+3]);
        }
        dst0[32] = den0;
        dst1[32] = den1;
    }
}

// One block per b: sum partials over the 256 blocks, divide, store out.
__global__ __launch_bounds__(256) void gmm_reduce(
    const float* __restrict__ part,
    float* __restrict__ out)
{
    const int b   = blockIdx.x;
    const int tid = threadIdx.x;            // 0..255 = source block index
    const float* __restrict__ src = part + tid * PART_PER_BLK + b * PS;

    float v[33];
#pragma unroll
    for (int c = 0; c < 8; ++c) {
        const float4 f = *(const float4*)(src + 4 * c);
        v[4*c+0] = f.x; v[4*c+1] = f.y; v[4*c+2] = f.z; v[4*c+3] = f.w;
    }
    v[32] = src[32];

#pragma unroll
    for (int m = 1; m < 64; m <<= 1) {
#pragma unroll
        for (int k = 0; k < 33; ++k) v[k] += __shfl_xor(v[k], m);
    }

    __shared__ float red[4][33];
    const int w = tid >> 6;
    const int l = tid & 63;
    if (l == 0) {
#pragma unroll
        for (int k = 0; k < 33; ++k) red[w][k] = v[k];
    }
    __syncthreads();

    if (tid < ND) {
        const float num = red[0][tid] + red[1][tid] + red[2][tid] + red[3][tid];
        const float den = red[0][32] + red[1][32] + red[2][32] + red[3][32];
        out[b * ND + tid] = num / den;
    }
}

extern "C" void kernel_launch(void* const* d_in, const int* in_sizes, int n_in,
                              void* d_out, int out_size, void* d_ws, size_t ws_size,
                              hipStream_t stream)
{
    const float* X   = (const float*)d_in[0];
    const float* t   = (const float*)d_in[1];
    const float* Mu0 = (const float*)d_in[2];
    const float* Mu1 = (const float*)d_in[3];
    const float* S0  = (const float*)d_in[4];
    const float* S1  = (const float*)d_in[5];
    const float* Lam = (const float*)d_in[6];
    float* out  = (float*)d_out;
    float* part = (float*)d_ws;             // NBLK * PART_PER_BLK floats (~4.5 MB)

    gmm_fused<<<NBLK, NTHR, 0, stream>>>(X, t, Mu0, Mu1, S0, S1, Lam, part);
    gmm_reduce<<<BB, 256, 0, stream>>>(part, out);
}